// Round 6
// baseline (11557.159 us; speedup 1.0000x reference)
//
#include <hip/hip_runtime.h>
#include <math.h>

#define BATCH 2048
#define STEPS 512
#define EMB   128
#define HID   256
#define INGRU 641          // EMB + STEPS + 1

// ws layout:
//   float4 Whp[64 k4][256 d][3 g] : Whp[..] = W_hh[g*256+d][4k4..4k4+3]
//   float4 Wxp[32 k4][256 d][3 g] : Wxp[..] = W_ih[g*256+d][4k4..4k4+3]
//   float  Wcol[513 c][768 gg]    : Wcol[c][gg] = W_ih[gg][EMB+c]
#define WXP_OFF  49152                      // float4 index (64*768)
#define WCOL_OFF 294912                     // float index

__global__ void prep_weights(const float* __restrict__ W_ih,
                             const float* __restrict__ W_hh,
                             float* __restrict__ ws) {
    const int idx = blockIdx.x * 256 + threadIdx.x;     // < 513*768
    float4* __restrict__ Wp = (float4*)ws;
    if (idx < 49152) {                 // Whp
        const int k4 = idx / 768, rem = idx % 768;
        const int d = rem / 3, g = rem % 3;
        Wp[idx] = *(const float4*)(W_hh + ((size_t)(g * 256 + d)) * HID + 4 * k4);
    }
    if (idx < 24576) {                 // Wxp (unaligned source rows)
        const int k4 = idx / 768, rem = idx % 768;
        const int d = rem / 3, g = rem % 3;
        const float* src = W_ih + ((size_t)(g * 256 + d)) * INGRU + 4 * k4;
        Wp[WXP_OFF + idx] = make_float4(src[0], src[1], src[2], src[3]);
    }
    if (idx < 513 * 768) {             // Wcol
        const int c = idx / 768, gg = idx % 768;
        ws[WCOL_OFF + (size_t)c * 768 + gg] = W_ih[(size_t)gg * INGRU + EMB + c];
    }
}

// ---- x-GEMM helpers (R5 verbatim; k-ascending chains preserved) ----
#define FMA8(ACC, S, A, B) do {                                           \
    ACC[0] = fmaf(S, (A).x, ACC[0]); ACC[1] = fmaf(S, (A).y, ACC[1]);     \
    ACC[2] = fmaf(S, (A).z, ACC[2]); ACC[3] = fmaf(S, (A).w, ACC[3]);     \
    ACC[4] = fmaf(S, (B).x, ACC[4]); ACC[5] = fmaf(S, (B).y, ACC[5]);     \
    ACC[6] = fmaf(S, (B).z, ACC[6]); ACC[7] = fmaf(S, (B).w, ACC[7]);     \
} while (0)

#define K1(A0, A1, A2, S0, S1, S2, HP, OFF) do {                          \
    const float4 hA = *(const float4*)((HP) + (OFF));                     \
    const float4 hB = *(const float4*)((HP) + (OFF) + 4);                 \
    FMA8(A0, S0, hA, hB); FMA8(A1, S1, hA, hB); FMA8(A2, S2, hA, hB);     \
} while (0)

#define CONS(A0, A1, A2, W0, W1, W2, HP) do {                             \
    K1(A0, A1, A2, (W0).x, (W1).x, (W2).x, HP, 0);                        \
    K1(A0, A1, A2, (W0).y, (W1).y, (W2).y, HP, 12);                       \
    K1(A0, A1, A2, (W0).z, (W1).z, (W2).z, HP, 24);                       \
    K1(A0, A1, A2, (W0).w, (W1).w, (W2).w, HP, 36);                       \
} while (0)

__device__ __forceinline__ float bcast_lane(float v, int lane) {
    return __uint_as_float(
        __builtin_amdgcn_readlane(__float_as_uint(v), lane));
}
__device__ __forceinline__ float f4e(const float4 v, int e) {
    return e == 0 ? v.x : e == 1 ? v.y : e == 2 ? v.z : v.w;
}

// One WG = 8 batch rows, persistent over 512 steps. 512 threads:
//   waves 0-3 (t<256, d=t)   : x-GEMM (K=128, LDS x) + gates + classifier
//   waves 4-7 (t>=256, d=t&255): h-GEMM (K=256) with h in REGISTERS,
//     broadcast per (k,j) via v_readlane (SGPR operand) -> LDS pipe ~idle.
// h copy per h-wave: hreg[m] = h[32*(lane>>3)+m][lane&7], reloaded from
// h2[64][33] (2-way bank = free) once per step. All fma chains, seeds,
// classifier tree, epilogue: bit-identical to the R1 kernel.
__global__ __launch_bounds__(512, 2) void gru_policy(
    const float* __restrict__ X,      // [B][STEPS][EMB]
    const float* __restrict__ ws,
    const float* __restrict__ b_ih,   // [768]
    const float* __restrict__ b_hh,   // [768]
    const float* __restrict__ W_cf,   // [2][256]
    const float* __restrict__ b_cf,   // [2]
    float* __restrict__ out)          // [B*STEPS] actions | [B*STEPS] pis
{
    const float4* __restrict__ Wp   = (const float4*)ws;
    const float*  __restrict__ Wcol = ws + WCOL_OFF;

    __shared__ __align__(16) float h2[2][64][33];   // [buf][8*kh+j][m], 16.9 KB
    __shared__ __align__(16) float x_lds[EMB][12];  // 6.1 KB
    __shared__ float ah_lds[3][8][256];             // 24.6 KB
    __shared__ __align__(16) float red[8][8];       // [j][w*2+c]

    const int t     = threadIdx.x;
    const int xduty = (t < 256);
    const int d     = t & 255;
    const int wv    = t >> 6;        // x-waves: 0..3
    const int lane  = t & 63;
    const size_t r0 = (size_t)blockIdx.x * 8;
    const size_t xstride = (size_t)STEPS * EMB;

    // per-thread constants (valid loads for all t)
    const float bh0 = b_hh[d], bh1 = b_hh[d + 256], bh2 = b_hh[d + 512];
    const float bi0 = b_ih[d], bi1 = b_ih[d + 256], bi2 = b_ih[d + 512];
    const float wcf0 = W_cf[d], wcf1 = W_cf[256 + d];
    const float bc0 = b_cf[0], bc1 = b_cf[1];

    int   tags[8];
    float hp[8];
    #pragma unroll
    for (int j = 0; j < 8; ++j) { tags[j] = 0; hp[j] = 0.0f; }

    // zero h2[0]; stage x for step 0
    for (int i = t; i < 64 * 33; i += 512) h2[0][i / 33][i % 33] = 0.0f;
    if (xduty) {
        #pragma unroll
        for (int q = 0; q < 4; ++q) {
            const int i = d + 256 * q, row = i >> 7, col = i & 127;
            x_lds[col][row] = X[(r0 + row) * xstride + col];
        }
    }
    __syncthreads();

    int cur = 0;
    for (int s = 0; s < STEPS; ++s) {
        float aI0[8], aI1[8], aI2[8];
        float xn[4];
        if (!xduty) {
            // ================= h-duty: K=256 register GEMM =================
            const float4* wp = Wp + (size_t)d * 3;
            float4 a0 = wp[0], a1 = wp[1], a2 = wp[2]; wp += 768;
            float4 b0 = wp[0], b1 = wp[1], b2 = wp[2]; wp += 768;

            float hreg[32];
            #pragma unroll
            for (int m = 0; m < 32; ++m) hreg[m] = h2[cur][lane][m];

            float aH0[8], aH1[8], aH2[8];
            #pragma unroll
            for (int j = 0; j < 8; ++j) { aH0[j] = bh0; aH1[j] = bh1; aH2[j] = bh2; }

            __builtin_amdgcn_s_setprio(1);
            #pragma unroll 1
            for (int kb = 0; kb < 8; ++kb) {        // runtime loop: I-cache
                const int lb = kb << 3;             // readlane base (uniform)
                #pragma unroll
                for (int m4 = 0; m4 < 8; ++m4) {    // static: k4 = kb*8+m4
                    float4 w0, w1, w2;
                    if ((m4 & 1) == 0) {
                        w0 = a0; w1 = a1; w2 = a2;
                        a0 = wp[0]; a1 = wp[1]; a2 = wp[2]; wp += 768; // overrun ok (in ws)
                    } else {
                        w0 = b0; w1 = b1; w2 = b2;
                        b0 = wp[0]; b1 = wp[1]; b2 = wp[2]; wp += 768;
                    }
                    #pragma unroll
                    for (int e = 0; e < 4; ++e) {   // k = 32*kb + 4*m4 + e
                        const float we0 = f4e(w0, e), we1 = f4e(w1, e), we2 = f4e(w2, e);
                        const int rm = (m4 << 2) | e;
                        #pragma unroll
                        for (int j = 0; j < 8; ++j) {
                            const float sv = bcast_lane(hreg[rm], lb + j);
                            aH0[j] = fmaf(we0, sv, aH0[j]);
                            aH1[j] = fmaf(we1, sv, aH1[j]);
                            aH2[j] = fmaf(we2, sv, aH2[j]);
                        }
                    }
                }
            }
            __builtin_amdgcn_s_setprio(0);
            #pragma unroll
            for (int j = 0; j < 8; ++j) {
                ah_lds[0][j][d] = aH0[j];
                ah_lds[1][j][d] = aH1[j];
                ah_lds[2][j][d] = aH2[j];
            }
        } else {
            // ========= x-duty: gather + next-x loads + K=128 GEMM =========
            #pragma unroll
            for (int j = 0; j < 8; ++j) {
                const size_t tg = (size_t)tags[j] * 768;
                aI0[j] = bi0 + Wcol[tg + d];
                aI1[j] = bi1 + Wcol[tg + 256 + d];
                aI2[j] = bi2 + Wcol[tg + 512 + d];
            }
            if (s + 1 < STEPS) {
                #pragma unroll
                for (int q = 0; q < 4; ++q) {
                    const int i = d + 256 * q, row = i >> 7, col = i & 127;
                    xn[q] = X[(r0 + row) * xstride + (size_t)(s + 1) * EMB + col];
                }
            }
            const float* xb = &x_lds[0][0];
            const float4* wq = Wp + WXP_OFF + (size_t)d * 3;
            float4 a0 = wq[0], a1 = wq[1], a2 = wq[2]; wq += 768;
            float4 b0 = wq[0], b1 = wq[1], b2 = wq[2]; wq += 768;
            #pragma unroll 2
            for (int it = 0; it < 30; it += 2) {
                const float4 c0 = wq[0], c1 = wq[1], c2 = wq[2]; wq += 768;
                const float4 e0 = wq[0], e1 = wq[1], e2 = wq[2]; wq += 768;
                CONS(aI0, aI1, aI2, a0, a1, a2, xb + it * 48);
                CONS(aI0, aI1, aI2, b0, b1, b2, xb + it * 48 + 48);
                a0 = c0; a1 = c1; a2 = c2; b0 = e0; b1 = e1; b2 = e2;
            }
            CONS(aI0, aI1, aI2, a0, a1, a2, xb + 30 * 48);
            CONS(aI0, aI1, aI2, b0, b1, b2, xb + 31 * 48);
            // aI stays in registers (no publish)
        }
        __syncthreads();   // B1: ah_lds ready; x_lds reads done

        if (xduty) {
            // ---- gates, h_new, classifier (R1 formulas & tree) ----
            float p0[8], p1[8];
            #pragma unroll
            for (int j = 0; j < 8; ++j) {
                const float ah0 = ah_lds[0][j][d];
                const float ah1 = ah_lds[1][j][d];
                const float ah2 = ah_lds[2][j][d];
                const float rr = 1.0f / (1.0f + expf(-(aI0[j] + ah0)));
                const float zz = 1.0f / (1.0f + expf(-(aI1[j] + ah1)));
                const float nn = tanhf(aI2[j] + rr * ah2);
                const float h  = (1.0f - zz) * nn + zz * hp[j];
                hp[j] = h;
                h2[cur ^ 1][((d >> 5) << 3) | j][d & 31] = h;
                p0[j] = h * wcf0;
                p1[j] = h * wcf1;
            }
            #pragma unroll
            for (int m = 32; m >= 1; m >>= 1) {
                #pragma unroll
                for (int j = 0; j < 8; ++j) {
                    p0[j] += __shfl_xor(p0[j], m, 64);
                    p1[j] += __shfl_xor(p1[j], m, 64);
                }
            }
            if (lane == 0) {
                #pragma unroll
                for (int j = 0; j < 8; ++j) {
                    red[j][wv * 2]     = p0[j];
                    red[j][wv * 2 + 1] = p1[j];
                }
            }
            if (s + 1 < STEPS) {   // stage next x (reads done before B1)
                #pragma unroll
                for (int q = 0; q < 4; ++q) {
                    const int i = d + 256 * q, row = i >> 7, col = i & 127;
                    x_lds[col][row] = xn[q];
                }
            }
        }
        __syncthreads();   // B2: h2[nxt], red, x staged

        if (xduty) {
            // every x-thread tracks all 8 tags locally (no 3rd barrier)
            #pragma unroll
            for (int j = 0; j < 8; ++j) {
                const float4 rA = *(const float4*)&red[j][0];
                const float4 rB = *(const float4*)&red[j][4];
                float l0 = bc0; l0 += rA.x; l0 += rA.z; l0 += rB.x; l0 += rB.z;
                float l1 = bc1; l1 += rA.y; l1 += rA.w; l1 += rB.y; l1 += rB.w;
                const int act = (l1 > l0) ? 1 : 0;
                tags[j] += act;
                if (t == j) {
                    const float mx = fmaxf(l0, l1);
                    const float e0 = expf(l0 - mx), e1 = expf(l1 - mx);
                    const float pi = (act ? e1 : e0) / (e0 + e1);
                    const size_t row = r0 + j;
                    out[row * STEPS + s] = (float)act;
                    out[(size_t)BATCH * STEPS + row * STEPS + s] = pi;
                }
            }
        }
        cur ^= 1;
    }
}

extern "C" void kernel_launch(void* const* d_in, const int* in_sizes, int n_in,
                              void* d_out, int out_size, void* d_ws, size_t ws_size,
                              hipStream_t stream) {
    const float* X    = (const float*)d_in[0];
    const float* W_ih = (const float*)d_in[1];
    const float* W_hh = (const float*)d_in[2];
    const float* b_ih = (const float*)d_in[3];
    const float* b_hh = (const float*)d_in[4];
    const float* W_cf = (const float*)d_in[5];
    const float* b_cf = (const float*)d_in[6];
    float* out = (float*)d_out;
    float* ws  = (float*)d_ws;

    prep_weights<<<1539, 256, 0, stream>>>(W_ih, W_hh, ws);
    gru_policy<<<BATCH / 8, 512, 0, stream>>>(X, ws, b_ih, b_hh, W_cf, b_cf, out);
}

// Round 7
// 10055.138 us; speedup vs baseline: 1.1494x; 1.1494x over previous
//
#include <hip/hip_runtime.h>
#include <math.h>

#define BATCH 2048
#define STEPS 512
#define EMB   128
#define HID   256
#define INGRU 641          // EMB + STEPS + 1

// ws layout (same as R5):
//   float4 Whp[64 k4][256 d][3 g] : Whp[..] = W_hh[g*256+d][4k4..4k4+3]
//   float4 Wxp[32 k4][256 d][3 g] : Wxp[..] = W_ih[g*256+d][4k4..4k4+3]
//   float  Wcol[513 c][768 gg]    : Wcol[c][gg] = W_ih[gg][EMB+c]
#define WXP_OFF  49152                      // float4 index (64*768)
#define WCOL_OFF 294912                     // float index

__global__ void prep_weights(const float* __restrict__ W_ih,
                             const float* __restrict__ W_hh,
                             float* __restrict__ ws) {
    const int idx = blockIdx.x * 256 + threadIdx.x;     // < 513*768
    float4* __restrict__ Wp = (float4*)ws;
    if (idx < 49152) {                 // Whp
        const int k4 = idx / 768, rem = idx % 768;
        const int d = rem / 3, g = rem % 3;
        Wp[idx] = *(const float4*)(W_hh + ((size_t)(g * 256 + d)) * HID + 4 * k4);
    }
    if (idx < 24576) {                 // Wxp (unaligned source rows)
        const int k4 = idx / 768, rem = idx % 768;
        const int d = rem / 3, g = rem % 3;
        const float* src = W_ih + ((size_t)(g * 256 + d)) * INGRU + 4 * k4;
        Wp[WXP_OFF + idx] = make_float4(src[0], src[1], src[2], src[3]);
    }
    if (idx < 513 * 768) {             // Wcol
        const int c = idx / 768, gg = idx % 768;
        ws[WCOL_OFF + (size_t)c * 768 + gg] = W_ih[(size_t)gg * INGRU + EMB + c];
    }
}

// ---- shared GEMM helpers (R5 verbatim; k-ascending chains preserved) ----
#define FMA8(ACC, S, A, B) do {                                           \
    ACC[0] = fmaf(S, (A).x, ACC[0]); ACC[1] = fmaf(S, (A).y, ACC[1]);     \
    ACC[2] = fmaf(S, (A).z, ACC[2]); ACC[3] = fmaf(S, (A).w, ACC[3]);     \
    ACC[4] = fmaf(S, (B).x, ACC[4]); ACC[5] = fmaf(S, (B).y, ACC[5]);     \
    ACC[6] = fmaf(S, (B).z, ACC[6]); ACC[7] = fmaf(S, (B).w, ACC[7]);     \
} while (0)

#define K1(A0, A1, A2, S0, S1, S2, HP, OFF) do {                          \
    const float4 hA = *(const float4*)((HP) + (OFF));                     \
    const float4 hB = *(const float4*)((HP) + (OFF) + 4);                 \
    FMA8(A0, S0, hA, hB); FMA8(A1, S1, hA, hB); FMA8(A2, S2, hA, hB);     \
} while (0)

#define CONS(A0, A1, A2, W0, W1, W2, HP) do {                             \
    K1(A0, A1, A2, (W0).x, (W1).x, (W2).x, HP, 0);                        \
    K1(A0, A1, A2, (W0).y, (W1).y, (W2).y, HP, 12);                       \
    K1(A0, A1, A2, (W0).z, (W1).z, (W2).z, HP, 24);                       \
    K1(A0, A1, A2, (W0).w, (W1).w, (W2).w, HP, 36);                       \
} while (0)

__device__ __forceinline__ float bcast_lane(float v, int lane) {
    return __uint_as_float(
        __builtin_amdgcn_readlane(__float_as_uint(v), lane));
}

// readlane consumption of one k (weight elem E of the three float4s):
// h value for (k, j) lives in hreg[M] of lane lb+j.
#define RLK(W0, W1, W2, E, M, LB) do {                                    \
    const float we0 = (W0).E, we1 = (W1).E, we2 = (W2).E;                 \
    _Pragma("unroll")                                                     \
    for (int j = 0; j < 8; ++j) {                                         \
        const float sv = bcast_lane(hreg[M], (LB) + j);                   \
        aH0[j] = fmaf(we0, sv, aH0[j]);                                   \
        aH1[j] = fmaf(we1, sv, aH1[j]);                                   \
        aH2[j] = fmaf(we2, sv, aH2[j]);                                   \
    }                                                                     \
} while (0)

// One WG = 8 batch rows, persistent over 512 steps. 512 threads:
//   waves 0-3 (t<256, d=t)    : x-GEMM (K=128, LDS) + gates + classifier
//   waves 4-7 (t>=256, d=t&255): h-GEMM (K=256) with HYBRID transport:
//     k in [0,128):  LDS broadcast ds_read_b128 (R5 path, LDS pipe)
//     k in [128,256): register h + readlane       (R6 path, VALU pipe)
// Chain order stays k=0..255 ascending per (row, gate) -> bit-identical
// to the R1 kernel. hreg[m] of lane l holds h[128+16*(l>>3)+m][l&7];
// h[k][j] for k=128+16q+m is readlane(hreg[m], 8q+j).
__global__ __launch_bounds__(512, 2) void gru_policy(
    const float* __restrict__ X,      // [B][STEPS][EMB]
    const float* __restrict__ ws,
    const float* __restrict__ b_ih,   // [768]
    const float* __restrict__ b_hh,   // [768]
    const float* __restrict__ W_cf,   // [2][256]
    const float* __restrict__ b_cf,   // [2]
    float* __restrict__ out)          // [B*STEPS] actions | [B*STEPS] pis
{
    const float4* __restrict__ Wp   = (const float4*)ws;
    const float*  __restrict__ Wcol = ws + WCOL_OFF;

    __shared__ __align__(16) float h_lds[2][HID][12];   // 24.6 KB
    __shared__ __align__(16) float x_lds[EMB][12];      //  6.1 KB
    __shared__ float ah_lds[3][8][256];                 // 24.6 KB
    __shared__ __align__(16) float red[8][8];           // [j][wv*2+c]

    const int t     = threadIdx.x;
    const int xduty = (t < 256);
    const int d     = t & 255;
    const int wv    = t >> 6;        // x-waves: 0..3
    const int lane  = t & 63;
    const size_t r0 = (size_t)blockIdx.x * 8;
    const size_t xstride = (size_t)STEPS * EMB;

    const float bh0 = b_hh[d], bh1 = b_hh[d + 256], bh2 = b_hh[d + 512];
    const float bi0 = b_ih[d], bi1 = b_ih[d + 256], bi2 = b_ih[d + 512];
    const float wcf0 = W_cf[d], wcf1 = W_cf[256 + d];
    const float bc0 = b_cf[0], bc1 = b_cf[1];

    int   tags[8];
    float hp[8];
    #pragma unroll
    for (int j = 0; j < 8; ++j) { tags[j] = 0; hp[j] = 0.0f; }

    // init: zero h_lds[0]; stage x for step 0
    for (int i = t; i < HID * 8; i += 512) h_lds[0][i >> 3][i & 7] = 0.0f;
    if (xduty) {
        #pragma unroll
        for (int q = 0; q < 4; ++q) {
            const int i = d + 256 * q, row = i >> 7, col = i & 127;
            x_lds[col][row] = X[(r0 + row) * xstride + col];
        }
    }
    __syncthreads();

    int cur = 0;
    for (int s = 0; s < STEPS; ++s) {
        float aI0[8], aI1[8], aI2[8];
        float xn[4];
        if (!xduty) {
            // ============ h-duty: K=256, hybrid transport ============
            float aH0[8], aH1[8], aH2[8];
            #pragma unroll
            for (int j = 0; j < 8; ++j) { aH0[j] = bh0; aH1[j] = bh1; aH2[j] = bh2; }

            // register copy of k in [128,256): 16 b32 gathers
            float hreg[16];
            {
                const int qg = lane >> 3, jj = lane & 7;
                #pragma unroll
                for (int m = 0; m < 16; ++m)
                    hreg[m] = h_lds[cur][128 + 16 * qg + m][jj];
            }

            __builtin_amdgcn_s_setprio(1);
            // ---- phase 1: k = 0..127 via LDS broadcast (R5 loop) ----
            {
                const float* hb = &h_lds[cur][0][0];
                const float4* wp = Wp + (size_t)d * 3;     // Whp, k4=0
                float4 a0 = wp[0], a1 = wp[1], a2 = wp[2]; wp += 768;
                float4 b0 = wp[0], b1 = wp[1], b2 = wp[2]; wp += 768;
                #pragma unroll 2
                for (int it = 0; it < 30; it += 2) {
                    const float4 c0 = wp[0], c1 = wp[1], c2 = wp[2]; wp += 768;
                    const float4 e0 = wp[0], e1 = wp[1], e2 = wp[2]; wp += 768;
                    CONS(aH0, aH1, aH2, a0, a1, a2, hb + it * 48);
                    CONS(aH0, aH1, aH2, b0, b1, b2, hb + it * 48 + 48);
                    a0 = c0; a1 = c1; a2 = c2; b0 = e0; b1 = e1; b2 = e2;
                }
                CONS(aH0, aH1, aH2, a0, a1, a2, hb + 30 * 48);
                CONS(aH0, aH1, aH2, b0, b1, b2, hb + 31 * 48);
            }
            // ---- phase 2: k = 128..255 via readlane (VALU pipe) ----
            #pragma unroll 1
            for (int q = 0; q < 8; ++q) {       // k = 128 + 16q + m
                const int lb = q << 3;          // uniform lane base
                const float4* wq = Wp + (size_t)(32 + 4 * q) * 768 + (size_t)d * 3;
                #pragma unroll
                for (int mg = 0; mg < 4; ++mg) {    // k4 = 32+4q+mg
                    const float4 w0 = wq[mg * 768];
                    const float4 w1 = wq[mg * 768 + 1];
                    const float4 w2 = wq[mg * 768 + 2];
                    RLK(w0, w1, w2, x, 4 * mg + 0, lb);
                    RLK(w0, w1, w2, y, 4 * mg + 1, lb);
                    RLK(w0, w1, w2, z, 4 * mg + 2, lb);
                    RLK(w0, w1, w2, w, 4 * mg + 3, lb);
                }
            }
            __builtin_amdgcn_s_setprio(0);
            #pragma unroll
            for (int j = 0; j < 8; ++j) {
                ah_lds[0][j][d] = aH0[j];
                ah_lds[1][j][d] = aH1[j];
                ah_lds[2][j][d] = aH2[j];
            }
        } else {
            // ========= x-duty: gather + next-x loads + K=128 GEMM =========
            #pragma unroll
            for (int j = 0; j < 8; ++j) {
                const size_t tg = (size_t)tags[j] * 768;
                aI0[j] = bi0 + Wcol[tg + d];
                aI1[j] = bi1 + Wcol[tg + 256 + d];
                aI2[j] = bi2 + Wcol[tg + 512 + d];
            }
            if (s + 1 < STEPS) {
                #pragma unroll
                for (int q = 0; q < 4; ++q) {
                    const int i = d + 256 * q, row = i >> 7, col = i & 127;
                    xn[q] = X[(r0 + row) * xstride + (size_t)(s + 1) * EMB + col];
                }
            }
            const float* xb = &x_lds[0][0];
            const float4* wq = Wp + WXP_OFF + (size_t)d * 3;
            float4 a0 = wq[0], a1 = wq[1], a2 = wq[2]; wq += 768;
            float4 b0 = wq[0], b1 = wq[1], b2 = wq[2]; wq += 768;
            #pragma unroll 2
            for (int it = 0; it < 30; it += 2) {
                const float4 c0 = wq[0], c1 = wq[1], c2 = wq[2]; wq += 768;
                const float4 e0 = wq[0], e1 = wq[1], e2 = wq[2]; wq += 768;
                CONS(aI0, aI1, aI2, a0, a1, a2, xb + it * 48);
                CONS(aI0, aI1, aI2, b0, b1, b2, xb + it * 48 + 48);
                a0 = c0; a1 = c1; a2 = c2; b0 = e0; b1 = e1; b2 = e2;
            }
            CONS(aI0, aI1, aI2, a0, a1, a2, xb + 30 * 48);
            CONS(aI0, aI1, aI2, b0, b1, b2, xb + 31 * 48);
        }
        __syncthreads();   // B1: ah_lds ready; x_lds/h_lds[cur] reads done

        if (xduty) {
            // ---- gates, h_new, classifier (R1 formulas & tree) ----
            float p0[8], p1[8], hn[8];
            #pragma unroll
            for (int j = 0; j < 8; ++j) {
                const float ah0 = ah_lds[0][j][d];
                const float ah1 = ah_lds[1][j][d];
                const float ah2 = ah_lds[2][j][d];
                const float rr = 1.0f / (1.0f + expf(-(aI0[j] + ah0)));
                const float zz = 1.0f / (1.0f + expf(-(aI1[j] + ah1)));
                const float nn = tanhf(aI2[j] + rr * ah2);
                const float h  = (1.0f - zz) * nn + zz * hp[j];
                hp[j] = h;
                hn[j] = h;
                p0[j] = h * wcf0;
                p1[j] = h * wcf1;
            }
            *(float4*)(&h_lds[cur ^ 1][d][0]) =
                make_float4(hn[0], hn[1], hn[2], hn[3]);
            *(float4*)(&h_lds[cur ^ 1][d][4]) =
                make_float4(hn[4], hn[5], hn[6], hn[7]);
            #pragma unroll
            for (int m = 32; m >= 1; m >>= 1) {
                #pragma unroll
                for (int j = 0; j < 8; ++j) {
                    p0[j] += __shfl_xor(p0[j], m, 64);
                    p1[j] += __shfl_xor(p1[j], m, 64);
                }
            }
            if (lane == 0) {
                #pragma unroll
                for (int j = 0; j < 8; ++j) {
                    red[j][wv * 2]     = p0[j];
                    red[j][wv * 2 + 1] = p1[j];
                }
            }
            if (s + 1 < STEPS) {   // stage next x (reads done before B1)
                #pragma unroll
                for (int q = 0; q < 4; ++q) {
                    const int i = d + 256 * q, row = i >> 7, col = i & 127;
                    x_lds[col][row] = xn[q];
                }
            }
        }
        __syncthreads();   // B2: h_lds[nxt], red, x staged

        if (xduty) {
            // every x-thread tracks all 8 tags locally (no 3rd barrier)
            #pragma unroll
            for (int j = 0; j < 8; ++j) {
                const float4 rA = *(const float4*)&red[j][0];
                const float4 rB = *(const float4*)&red[j][4];
                float l0 = bc0; l0 += rA.x; l0 += rA.z; l0 += rB.x; l0 += rB.z;
                float l1 = bc1; l1 += rA.y; l1 += rA.w; l1 += rB.y; l1 += rB.w;
                const int act = (l1 > l0) ? 1 : 0;
                tags[j] += act;
                if (t == j) {
                    const float mx = fmaxf(l0, l1);
                    const float e0 = expf(l0 - mx), e1 = expf(l1 - mx);
                    const float pi = (act ? e1 : e0) / (e0 + e1);
                    const size_t row = r0 + j;
                    out[row * STEPS + s] = (float)act;
                    out[(size_t)BATCH * STEPS + row * STEPS + s] = pi;
                }
            }
        }
        cur ^= 1;
    }
}

extern "C" void kernel_launch(void* const* d_in, const int* in_sizes, int n_in,
                              void* d_out, int out_size, void* d_ws, size_t ws_size,
                              hipStream_t stream) {
    const float* X    = (const float*)d_in[0];
    const float* W_ih = (const float*)d_in[1];
    const float* W_hh = (const float*)d_in[2];
    const float* b_ih = (const float*)d_in[3];
    const float* b_hh = (const float*)d_in[4];
    const float* W_cf = (const float*)d_in[5];
    const float* b_cf = (const float*)d_in[6];
    float* out = (float*)d_out;
    float* ws  = (float*)d_ws;

    prep_weights<<<1539, 256, 0, stream>>>(W_ih, W_hh, ws);
    gru_policy<<<BATCH / 8, 512, 0, stream>>>(X, ws, b_ih, b_hh, W_cf, b_cf, out);
}